// Round 10
// baseline (317.193 us; speedup 1.0000x reference)
//
#include <hip/hip_runtime.h>
#include <hip/hip_bf16.h>
#include <vector>
#include <cmath>
#include <cstring>

using bf16 = __hip_bfloat16;
typedef short s16x8 __attribute__((ext_vector_type(8)));
typedef float f32x4 __attribute__((ext_vector_type(4)));

static constexpr int kH = 16, kD = 128, kNB = 1024, kML = 512, kQL = 2048, kDM = 2048;

// ================= host precompute of Gt (input-independent) =================
// Gt[n][l] = G[l][n] where G = (rows 256..767 of) solve(FF^T+0.5I, F)^T
static void compute_Gt_host(float* Gt) {
  const int n = kNB, P = 2 * kML;
  std::vector<double> F((size_t)n * P), A((size_t)n * n), pos(P);
  const double shift = 1.0 / (double)P;
  const double p0 = -0.5 + shift, p1 = 1.5 - shift;
  for (int i = 0; i < P; i++) pos[i] = p0 + (p1 - p0) * (double)i / (double)(P - 1);
  const double c0 = 0.3989422804014327;
  std::vector<int> lo(n), hi(n);
  for (int b = 0; b < n; b++) {
    double mu = (double)(b >> 1) / 511.0;
    double sg = (b & 1) ? 0.01 : 0.005;
    double c = c0 / sg;
    double* Fb = &F[(size_t)b * P];
    for (int i = 0; i < P; i++) { double t = (pos[i] - mu) / sg; Fb[i] = c * exp(-0.5 * t * t); }
    int l = 0; while (l < P - 1 && pos[l] < mu - 14.0 * sg) l++;
    int h = P - 1; while (h > 0 && pos[h] > mu + 14.0 * sg) h--;
    lo[b] = l; hi[b] = h;
  }
  for (int i = 0; i < n; i++) {
    const double* fi = &F[(size_t)i * P];
    for (int j = 0; j <= i; j++) {
      const double* fj = &F[(size_t)j * P];
      int a = lo[i] > lo[j] ? lo[i] : lo[j];
      int b2 = hi[i] < hi[j] ? hi[i] : hi[j];
      double s = 0.0;
      for (int k2 = a; k2 <= b2; k2++) s += fi[k2] * fj[k2];
      A[(size_t)i * n + j] = s;
      if (i != j) A[(size_t)j * n + i] = s;
    }
    A[(size_t)i * n + i] += 0.5;
  }
  for (int j = 0; j < n; j++) {  // Cholesky
    double* Aj = &A[(size_t)j * n];
    double d = Aj[j];
    for (int k2 = 0; k2 < j; k2++) d -= Aj[k2] * Aj[k2];
    d = std::sqrt(d); Aj[j] = d;
    double inv = 1.0 / d;
    for (int i = j + 1; i < n; i++) {
      double* Ai = &A[(size_t)i * n];
      double s = Ai[j];
      for (int k2 = 0; k2 < j; k2++) s -= Ai[k2] * Aj[k2];
      Ai[j] = s * inv;
    }
  }
  for (int i = 0; i < n; i++) {  // L Y = F
    double* yi = &F[(size_t)i * P];
    const double* Ai = &A[(size_t)i * n];
    for (int k2 = 0; k2 < i; k2++) {
      double lik = Ai[k2];
      const double* yk = &F[(size_t)k2 * P];
      for (int t = 0; t < P; t++) yi[t] -= lik * yk[t];
    }
    double inv = 1.0 / Ai[i];
    for (int t = 0; t < P; t++) yi[t] *= inv;
  }
  for (int i = n - 1; i >= 0; i--) {  // L^T X = Y
    double* xi = &F[(size_t)i * P];
    for (int k2 = i + 1; k2 < n; k2++) {
      double lki = A[(size_t)k2 * n + i];
      const double* xk = &F[(size_t)k2 * P];
      for (int t = 0; t < P; t++) xi[t] -= lki * xk[t];
    }
    double inv = 1.0 / A[(size_t)i * n + i];
    for (int t = 0; t < P; t++) xi[t] *= inv;
  }
  for (int b = 0; b < n; b++)
    for (int l = 0; l < kML; l++)
      Gt[(size_t)b * kML + l] = (float)F[(size_t)b * P + (kML / 2) + l];
}

static unsigned short f2bf_host(float x) {
  unsigned u; std::memcpy(&u, &x, 4);
  unsigned r = (u + 0x7FFFu + ((u >> 16) & 1u)) >> 16;
  return (unsigned short)r;
}
static float bf2f_host(unsigned short b) {
  unsigned u = ((unsigned)b) << 16; float f; std::memcpy(&f, &u, 4); return f;
}

namespace {
struct Init {
  float* d_GtTf = nullptr;           // f32 GtT[l][n]  [512][1024] (gw path, coalesced)
  unsigned short* d_Gth = nullptr;   // bf16-hi Gt[n][l]  [1024][512]
  unsigned short* d_Gtl = nullptr;   // bf16-lo Gt[n][l]  [1024][512]
  float* h_GtTf_pinned = nullptr;
  unsigned short* h_Gth_pinned = nullptr;
  unsigned short* h_Gtl_pinned = nullptr;
  std::vector<float> h_GtTf;
  std::vector<unsigned short> h_Gth, h_Gtl;
  Init() {
    std::vector<float> h_Gt((size_t)kNB * kML);
    compute_Gt_host(h_Gt.data());
    h_GtTf.resize(h_Gt.size());
    h_Gth.resize(h_Gt.size());
    h_Gtl.resize(h_Gt.size());
    for (int n = 0; n < kNB; n++)
      for (int l = 0; l < kML; l++) {
        float v = h_Gt[(size_t)n * kML + l];
        h_GtTf[(size_t)l * kNB + n] = v;
        unsigned short hb = f2bf_host(v);
        h_Gth[(size_t)n * kML + l] = hb;
        h_Gtl[(size_t)n * kML + l] = f2bf_host(v - bf2f_host(hb));
      }
    const size_t fb = h_Gt.size() * 4, bb = h_Gt.size() * 2;
    if (hipMalloc((void**)&d_GtTf, fb) == hipSuccess) {
      if (hipMemcpy(d_GtTf, h_GtTf.data(), fb, hipMemcpyHostToDevice) != hipSuccess) { hipFree(d_GtTf); d_GtTf = nullptr; }
    }
    if (hipMalloc((void**)&d_Gth, bb) == hipSuccess) {
      if (hipMemcpy(d_Gth, h_Gth.data(), bb, hipMemcpyHostToDevice) != hipSuccess) { hipFree(d_Gth); d_Gth = nullptr; }
    }
    if (hipMalloc((void**)&d_Gtl, bb) == hipSuccess) {
      if (hipMemcpy(d_Gtl, h_Gtl.data(), bb, hipMemcpyHostToDevice) != hipSuccess) { hipFree(d_Gtl); d_Gtl = nullptr; }
    }
    if (!d_GtTf && hipHostMalloc((void**)&h_GtTf_pinned, fb, 0) == hipSuccess)
      std::memcpy(h_GtTf_pinned, h_GtTf.data(), fb);
    if (!d_Gth && hipHostMalloc((void**)&h_Gth_pinned, bb, 0) == hipSuccess)
      std::memcpy(h_Gth_pinned, h_Gth.data(), bb);
    if (!d_Gtl && hipHostMalloc((void**)&h_Gtl_pinned, bb, 0) == hipSuccess)
      std::memcpy(h_Gtl_pinned, h_Gtl.data(), bb);
  }
};
Init g_init;
}

// ================= device helpers =================
__device__ inline short f2bf(float x) {
  unsigned u = __float_as_uint(x);
  unsigned r = (u + 0x7FFFu + ((u >> 16) & 1u)) >> 16;
  return (short)r;
}
__device__ inline float bf2f(short b) {
  return __uint_as_float(((unsigned)(unsigned short)b) << 16);
}

// async global->LDS, 16 B per lane; LDS dest is wave-uniform base + lane*16.
// Per-lane GLOBAL address is pre-permuted so that linear lane order reproduces
// the fragment layout: slot l holds (row = l&15, k-chunk = l>>4).
__device__ inline void gload16(const void* g, void* l) {
  __builtin_amdgcn_global_load_lds(
      (__attribute__((address_space(1))) void*)(g),
      (__attribute__((address_space(3))) void*)(l),
      16, 0, 0);
}

// ================= dtype detection =================
__global__ __launch_bounds__(256) void detect_kernel(const unsigned short* __restrict__ q,
                                                     int* __restrict__ flag) {
  int t = threadIdx.x;
  int bad = 0;
  for (int i = t; i < 4096; i += 256) {
    int e = (q[i] >> 7) & 0xFF;
    if (e >= 0x98) bad = 1;
  }
  __shared__ int s[256];
  s[t] = bad; __syncthreads();
  for (int k2 = 128; k2 > 0; k2 >>= 1) { if (t < k2) s[t] |= s[t + k2]; __syncthreads(); }
  if (t == 0) *flag = s[0];  // 1 => float32 inputs
}

// elementwise convert (f32|bf16 in) -> bf16, 4 elems/thread
__global__ __launch_bounds__(256) void conv_bf16(const void* __restrict__ in,
                                                 short* __restrict__ out, int n4,
                                                 const int* __restrict__ flag) {
  int i = blockIdx.x * 256 + threadIdx.x;
  if (i >= n4) return;
  if (*flag) {
    float4 v = ((const float4*)in)[i];
    short4 o; o.x = f2bf(v.x); o.y = f2bf(v.y); o.z = f2bf(v.z); o.w = f2bf(v.w);
    ((short4*)out)[i] = o;
  } else {
    ((short4*)out)[i] = ((const short4*)in)[i];
  }
}

// ===== exact f32 mu/sigma path (well-conditioned: random-weight sums only) =====
// gw[l] = sum_n GtT[l][n] * w[n]  -- one block per l, coalesced row reads
__global__ __launch_bounds__(256) void gw_kernel(const float* __restrict__ GtT,
                                                 const void* __restrict__ wmu,
                                                 const void* __restrict__ wsg,
                                                 float* __restrict__ gw,
                                                 const int* __restrict__ flag) {
  const bool f32 = (*flag != 0);
  const int l = blockIdx.x, t = threadIdx.x;
  const float* row = GtT + (long long)l * kNB;
  float a = 0.f, b = 0.f;
  for (int n = t; n < kNB; n += 256) {
    float g = row[n];
    float wm_ = f32 ? ((const float*)wmu)[n] : bf2f(((const short*)wmu)[n]);
    float ws_ = f32 ? ((const float*)wsg)[n] : bf2f(((const short*)wsg)[n]);
    a += g * wm_; b += g * ws_;
  }
  __shared__ float red[2][256];
  red[0][t] = a; red[1][t] = b;
  __syncthreads();
  for (int s = 128; s > 0; s >>= 1) {
    if (t < s) { red[0][t] += red[0][t + s]; red[1][t] += red[1][t + s]; }
    __syncthreads();
  }
  if (t == 0) { gw[l] = red[0][0]; gw[kML + l] = red[1][0]; }
}

// bw[j] += sum_{l in chunk} k[l][j] * gw[l]  -- grid (j-blocks, l-chunks), atomic combine
__global__ __launch_bounds__(256) void bwk_kernel(const void* __restrict__ kin,
                                                  const float* __restrict__ gw,
                                                  float* __restrict__ bw,
                                                  const int* __restrict__ flag) {
  const bool f32 = (*flag != 0);
  int j = blockIdx.x * 256 + threadIdx.x;
  int l0 = blockIdx.y * 32;
  float a = 0.f, b = 0.f;
  for (int l = l0; l < l0 + 32; l++) {
    float kv = f32 ? ((const float*)kin)[(long long)l * kDM + j]
                   : bf2f(((const short*)kin)[(long long)l * kDM + j]);
    a += kv * gw[l]; b += kv * gw[kML + l];
  }
  atomicAdd(&bw[j], a);
  atomicAdd(&bw[kDM + j], b);
}

__global__ __launch_bounds__(256) void kw_kernel(const void* __restrict__ Wk,
                                                 const float* __restrict__ bw,
                                                 float* __restrict__ kw,
                                                 const int* __restrict__ flag) {
  const bool f32 = (*flag != 0);
  int i = blockIdx.x;
  float smu = 0.f, ssg = 0.f;
  if (f32) {
    const float* row = (const float*)Wk + (long long)i * kDM;
    for (int j = threadIdx.x; j < kDM; j += 256) { float w = row[j]; smu += w * bw[j]; ssg += w * bw[kDM + j]; }
  } else {
    const short* row = (const short*)Wk + (long long)i * kDM;
    for (int j = threadIdx.x; j < kDM; j += 256) { float w = bf2f(row[j]); smu += w * bw[j]; ssg += w * bw[kDM + j]; }
  }
  __shared__ float red[2][256];
  red[0][threadIdx.x] = smu; red[1][threadIdx.x] = ssg;
  __syncthreads();
  for (int s = 128; s > 0; s >>= 1) {
    if (threadIdx.x < (unsigned)s) {
      red[0][threadIdx.x] += red[0][threadIdx.x + s];
      red[1][threadIdx.x] += red[1][threadIdx.x + s];
    }
    __syncthreads();
  }
  if (threadIdx.x == 0) { kw[i] = red[0][0]; kw[kDM + i] = red[1][0]; }
}

__global__ __launch_bounds__(256) void musig_kernel(const void* __restrict__ q,
                                                    const float* __restrict__ kw,
                                                    float* __restrict__ mu,
                                                    float* __restrict__ sigsq,
                                                    const int* __restrict__ flag) {
  const bool f32 = (*flag != 0);
  int w = threadIdx.x >> 6, lane = threadIdx.x & 63;
  int idx = blockIdx.x * 4 + w;  // h*2048 + q
  int h = idx >> 11;
  const float* kmu = kw + h * kD;
  const float* ksg = kw + kDM + h * kD;
  float q0, q1;
  if (f32) {
    const float* qrow = (const float*)q + (long long)idx * kD;
    q0 = qrow[lane]; q1 = qrow[lane + 64];
  } else {
    const short* qrow = (const short*)q + (long long)idx * kD;
    q0 = bf2f(qrow[lane]); q1 = bf2f(qrow[lane + 64]);
  }
  float a = q0 * kmu[lane] + q1 * kmu[lane + 64];
  float b = q0 * ksg[lane] + q1 * ksg[lane + 64];
  for (int s = 32; s > 0; s >>= 1) { a += __shfl_xor(a, s); b += __shfl_xor(b, s); }
  if (lane == 0) {
    const float inv_sqrt_d = 0.08838834764831845f;
    float zm = a * inv_sqrt_d, zs = b * inv_sqrt_d;
    mu[idx] = 1.f / (1.f + __expf(-zm));
    float sp = (zs > 20.f) ? zs : log1pf(__expf(zs));
    sigsq[idx] = fmaxf(sp, 1e-4f);
  }
}

// ===== MFMA GEMM: C[M,N] = A[M,K] @ BT[N,K]^T (bf16 in, f32 acc) ===============
// Tile 64x64, BK=64, double-buffered. Grid 1024 blocks -> 4 blocks/CU (LDS 32 KB
// allows 5): inter-block wave overlap hides per-step latency (the proven lever:
// 1->2 blocks/CU was +19%). MFMA K-order unchanged -> bit-identical C.
// CSTORE: 0 = bf16 row-major; 2 = runtime dtype (f32|bf16).
template <int CSTORE>
__global__ __launch_bounds__(256) void mfma_gemm_bt(
    const short* __restrict__ A0, int lda, long long sA,
    const short* __restrict__ BT0, int ldb, long long sB,
    void* __restrict__ C0, int ldc, long long sC,
    int K, const int* __restrict__ flag) {
  __shared__ s16x8 lA[2][512];  // [buf][ks*256 + sub*64 + lane]  8 KB/buf
  __shared__ s16x8 lB[2][512];
  const short* A = A0 + (long long)blockIdx.z * sA;
  const short* BT = BT0 + (long long)blockIdx.z * sB;
  const int t = threadIdx.x;
  const int wave = t >> 6, lane = t & 63;
  const int quad = lane >> 4, l16 = lane & 15;
  const int wm = wave >> 1, wn = wave & 1;
  const int m0 = blockIdx.y * 64, n0 = blockIdx.x * 64;
  const int srow = lane & 15, skc = lane >> 4;  // staging source (row, k-chunk)
  auto stage = [&](int b, int kk) {              // 4 gload16 per lane
    int m = wave * 16 + srow;                    // A/B subtiles 0..3, one per wave
#pragma unroll
    for (int ks = 0; ks < 2; ks++) {
      gload16(A + (long long)(m0 + m) * lda + kk + ks * 32 + skc * 8,
              &lA[b][ks * 256 + wave * 64]);
      gload16(BT + (long long)(n0 + m) * ldb + kk + ks * 32 + skc * 8,
              &lB[b][ks * 256 + wave * 64]);
    }
  };
  f32x4 acc[2][2];
  const f32x4 z = {0.f, 0.f, 0.f, 0.f};
#pragma unroll
  for (int i = 0; i < 2; i++)
#pragma unroll
    for (int j = 0; j < 2; j++) acc[i][j] = z;
  stage(0, 0);
  __syncthreads();
  int cur = 0;
  for (int k0 = 0; k0 < K; k0 += 64) {
    if (k0 + 64 < K) stage(cur ^ 1, k0 + 64);
#pragma unroll
    for (int ks = 0; ks < 2; ks++) {
      s16x8 af[2], bfr[2];
#pragma unroll
      for (int i = 0; i < 2; i++) af[i] = lA[cur][ks * 256 + (wm * 2 + i) * 64 + lane];
#pragma unroll
      for (int j = 0; j < 2; j++) bfr[j] = lB[cur][ks * 256 + (wn * 2 + j) * 64 + lane];
#pragma unroll
      for (int i = 0; i < 2; i++)
#pragma unroll
        for (int j = 0; j < 2; j++)
          acc[i][j] = __builtin_amdgcn_mfma_f32_16x16x32_bf16(af[i], bfr[j], acc[i][j], 0, 0, 0);
    }
    __syncthreads();
    cur ^= 1;
  }
  // epilogue: C/D layout col=lane&15, row=quad*4+reg
  if (CSTORE == 0) {
    short* Cp = (short*)C0 + (long long)blockIdx.z * sC;
#pragma unroll
    for (int i = 0; i < 2; i++)
#pragma unroll
      for (int j = 0; j < 2; j++) {
        int gn = n0 + (wn * 2 + j) * 16 + l16;
#pragma unroll
        for (int rg = 0; rg < 4; rg++) {
          int gm = m0 + (wm * 2 + i) * 16 + quad * 4 + rg;
          Cp[(long long)gm * ldc + gn] = f2bf(acc[i][j][rg]);
        }
      }
  } else {
    if (*flag) {
      float* Cp = (float*)C0 + (long long)blockIdx.z * sC;
#pragma unroll
      for (int i = 0; i < 2; i++)
#pragma unroll
        for (int j = 0; j < 2; j++) {
          int gn = n0 + (wn * 2 + j) * 16 + l16;
#pragma unroll
          for (int rg = 0; rg < 4; rg++) {
            int gm = m0 + (wm * 2 + i) * 16 + quad * 4 + rg;
            Cp[(long long)gm * ldc + gn] = acc[i][j][rg];
          }
        }
    } else {
      short* Cp = (short*)C0 + (long long)blockIdx.z * sC;
#pragma unroll
      for (int i = 0; i < 2; i++)
#pragma unroll
        for (int j = 0; j < 2; j++) {
          int gn = n0 + (wn * 2 + j) * 16 + l16;
#pragma unroll
          for (int rg = 0; rg < 4; rg++) {
            int gm = m0 + (wm * 2 + i) * 16 + quad * 4 + rg;
            Cp[(long long)gm * ldc + gn] = f2bf(acc[i][j][rg]);
          }
        }
    }
  }
}

// ===== split-K kv GEMM: P[z][l][d] = k[l][:] @ Wv[d][:] over K-chunk z ========
// Tile 64x64, BK=64, dbuf. Grid (32 d, 8 l, 4 K) = 1024 blocks -> 4/CU.
__global__ __launch_bounds__(256) void mfma_gemm_sk(
    const short* __restrict__ A0, int lda,      // k_bf [512][2048]
    const short* __restrict__ BT0, int ldb,     // Wv_bf [2048][2048]
    float* __restrict__ P, int ldc) {           // [4][512][2048] f32
  __shared__ s16x8 lA[2][512], lB[2][512];  // 32 KB
  const int t = threadIdx.x;
  const int wave = t >> 6, lane = t & 63;
  const int quad = lane >> 4, l16 = lane & 15;
  const int wm = wave >> 1, wn = wave & 1;
  const int m0 = blockIdx.y * 64, n0 = blockIdx.x * 64;
  const int kbeg = blockIdx.z * 512, kend = kbeg + 512;
  const int srow = lane & 15, skc = lane >> 4;
  auto stage = [&](int b, int kk) {
    int m = wave * 16 + srow;
#pragma unroll
    for (int ks = 0; ks < 2; ks++) {
      gload16(A0 + (long long)(m0 + m) * lda + kk + ks * 32 + skc * 8,
              &lA[b][ks * 256 + wave * 64]);
      gload16(BT0 + (long long)(n0 + m) * ldb + kk + ks * 32 + skc * 8,
              &lB[b][ks * 256 + wave * 64]);
    }
  };
  f32x4 acc[2][2];
  const f32x4 z = {0.f, 0.f, 0.f, 0.f};
#pragma unroll
  for (int i = 0; i < 2; i++)
#pragma unroll
    for (int j = 0; j < 2; j++) acc[i][j] = z;
  stage(0, kbeg);
  __syncthreads();
  int cur = 0;
  for (int k0 = kbeg; k0 < kend; k0 += 64) {
    if (k0 + 64 < kend) stage(cur ^ 1, k0 + 64);
#pragma unroll
    for (int ks = 0; ks < 2; ks++) {
      s16x8 af[2], bfr[2];
#pragma unroll
      for (int i = 0; i < 2; i++) af[i] = lA[cur][ks * 256 + (wm * 2 + i) * 64 + lane];
#pragma unroll
      for (int j = 0; j < 2; j++) bfr[j] = lB[cur][ks * 256 + (wn * 2 + j) * 64 + lane];
#pragma unroll
      for (int i = 0; i < 2; i++)
#pragma unroll
        for (int j = 0; j < 2; j++)
          acc[i][j] = __builtin_amdgcn_mfma_f32_16x16x32_bf16(af[i], bfr[j], acc[i][j], 0, 0, 0);
    }
    __syncthreads();
    cur ^= 1;
  }
  float* Cp = P + (long long)blockIdx.z * kML * kDM;
#pragma unroll
  for (int i = 0; i < 2; i++)
#pragma unroll
    for (int j = 0; j < 2; j++) {
      int gn = n0 + (wn * 2 + j) * 16 + l16;
#pragma unroll
      for (int rg = 0; rg < 4; rg++) {
        int gm = m0 + (wm * 2 + i) * 16 + quad * 4 + rg;
        Cp[(long long)gm * ldc + gn] = acc[i][j][rg];
      }
    }
}

// reduce 4 f32 partials [z][l][d] -> kvT bf16 [d][l] (LDS transpose, coalesced both sides)
__global__ __launch_bounds__(256) void reduceT_kernel(const float* __restrict__ P,
                                                      short* __restrict__ kvT) {
  __shared__ float tile[64][65];
  const int bd = blockIdx.x, bl = blockIdx.y;  // 32 x 8
  const int tx = threadIdx.x & 63, ty = threadIdx.x >> 6;
  for (int i = ty; i < 64; i += 4) {
    int l = bl * 64 + i, d = bd * 64 + tx;
    float s = 0.f;
#pragma unroll
    for (int z = 0; z < 4; z++) s += P[((long long)z * kML + l) * kDM + d];
    tile[i][tx] = s;
  }
  __syncthreads();
  for (int i = ty; i < 64; i += 4) {
    int d = bd * 64 + i, l = bl * 64 + tx;
    kvT[(long long)d * kML + l] = f2bf(tile[tx][i]);
  }
}

// ===== split-B GEMM with SPLIT OUTPUT ==========================================
// C[M,N] = A[M,K] @ (BTh+BTl)[N,K]^T, output split into Ch + Cl (bf16 pair).
// Tile 64x64, BK=32, dbuf. Grid (16 n, 32 m) = 512 blocks -> 2/CU. LDS 24 KB.
__global__ __launch_bounds__(256) void mfma_gemm_bt2(
    const short* __restrict__ A0, int lda,
    const short* __restrict__ BTh, const short* __restrict__ BTl, int ldb,
    short* __restrict__ Ch, short* __restrict__ Cl, int ldc, int K) {
  __shared__ s16x8 lA[2][256], lBh[2][256], lBl[2][256];  // 24 KB
  const int t = threadIdx.x;
  const int wave = t >> 6, lane = t & 63;
  const int quad = lane >> 4, l16 = lane & 15;
  const int wm = wave >> 1, wn = wave & 1;
  const int m0 = blockIdx.y * 64, n0 = blockIdx.x * 64;
  const int srow = lane & 15, skc = lane >> 4;
  auto stage = [&](int b, int kk) {
    int m = wave * 16 + srow;  // 4 subtiles each; one per wave
    gload16(A0 + (long long)(m0 + m) * lda + kk + skc * 8, &lA[b][wave * 64]);
    gload16(BTh + (long long)(n0 + m) * ldb + kk + skc * 8, &lBh[b][wave * 64]);
    gload16(BTl + (long long)(n0 + m) * ldb + kk + skc * 8, &lBl[b][wave * 64]);
  };
  f32x4 acc[2][2];
  const f32x4 z = {0.f, 0.f, 0.f, 0.f};
#pragma unroll
  for (int i = 0; i < 2; i++)
#pragma unroll
    for (int j = 0; j < 2; j++) acc[i][j] = z;
  stage(0, 0);
  __syncthreads();
  int cur = 0;
  for (int k0 = 0; k0 < K; k0 += 32) {
    if (k0 + 32 < K) stage(cur ^ 1, k0 + 32);
    s16x8 af[2], bh[2], bl[2];
#pragma unroll
    for (int i = 0; i < 2; i++) af[i] = lA[cur][(wm * 2 + i) * 64 + lane];
#pragma unroll
    for (int j = 0; j < 2; j++) {
      bh[j] = lBh[cur][(wn * 2 + j) * 64 + lane];
      bl[j] = lBl[cur][(wn * 2 + j) * 64 + lane];
    }
#pragma unroll
    for (int i = 0; i < 2; i++)
#pragma unroll
      for (int j = 0; j < 2; j++) {
        acc[i][j] = __builtin_amdgcn_mfma_f32_16x16x32_bf16(af[i], bh[j], acc[i][j], 0, 0, 0);
        acc[i][j] = __builtin_amdgcn_mfma_f32_16x16x32_bf16(af[i], bl[j], acc[i][j], 0, 0, 0);
      }
    __syncthreads();
    cur ^= 1;
  }
#pragma unroll
  for (int i = 0; i < 2; i++)
#pragma unroll
    for (int j = 0; j < 2; j++) {
      int gn = n0 + (wn * 2 + j) * 16 + l16;
#pragma unroll
      for (int rg = 0; rg < 4; rg++) {
        int gm = m0 + (wm * 2 + i) * 16 + quad * 4 + rg;
        float v = acc[i][j][rg];
        short hb = f2bf(v);
        Ch[(long long)gm * ldc + gn] = hb;
        Cl[(long long)gm * ldc + gn] = f2bf(v - bf2f(hb));
      }
    }
}

// ===== fused r-GEMM: ctx[q][h*128+d'] = sum_n r(h,q,n) * valuesT[h*128+d'][n] ===
// Tile 32 q-rows x 128 d-cols, BK=32, dbuf. Grid (1, 64 q-tiles, 16 heads) = 1024
// blocks -> 4/CU (LDS 40 KB allows 4). r generated on the fly (split rh+rl, 128
// active threads); VT via global_load_lds. 3 MFMA passes: rh*VTh+rh*VTl+rl*VTh.
__global__ __launch_bounds__(256) void mfma_rv(
    const float* __restrict__ mu_all, const float* __restrict__ s2_all,  // [16*2048]
    const short* __restrict__ VTh, const short* __restrict__ VTl,  // [2048][1024]
    short* __restrict__ ctx) {                                     // [2048][2048]
  __shared__ s16x8 lAh[2][128], lAl[2][128], lBh[2][512], lBl[2][512];  // 40 KB
  const int t = threadIdx.x;
  const int wave = t >> 6, lane = t & 63;
  const int quad = lane >> 4, l16 = lane & 15;
  const int wm = wave >> 1, wn = wave & 1;
  const int h = blockIdx.z;
  const int m0 = blockIdx.y * 32;  // q-rows within head
  const int r0 = (t & 127) >> 2, kc = t & 3;  // r0 in [0,32); threads t and t+128 duplicate
  const int srow = lane & 15, skc = lane >> 4;
  const long long voff = (long long)h * kD * kNB;
  const int row = h * kQL + m0 + r0;
  const float m_ = mu_all[row], s2 = s2_all[row];
  float ivs[2], cof[2];
  ivs[0] = rsqrtf(s2 + 2.5e-5f);  // b_sigma = 0.005 (even n)
  ivs[1] = rsqrtf(s2 + 1e-4f);    // b_sigma = 0.01  (odd n)
  cof[0] = 0.3989422804014327f * ivs[0];
  cof[1] = 0.3989422804014327f * ivs[1];
  const int cidx = (r0 >> 4) * 64 + kc * 16 + (r0 & 15);
  auto stageB = [&](int b, int kk) {  // 4 gload16 per lane
#pragma unroll
    for (int i = 0; i < 2; i++) {
      int sub = wave * 2 + i;  // B subtiles 0..7 (128 d-cols)
      int m = sub * 16 + srow;
      gload16(VTh + voff + (long long)m * kNB + kk + skc * 8, &lBh[b][sub * 64]);
      gload16(VTl + voff + (long long)m * kNB + kk + skc * 8, &lBl[b][sub * 64]);
    }
  };
  auto stageA = [&](int b, int kk) {  // threads <128 write one (row,chunk) each
    if (t < 128) {
      s16x8 hv, lv;
#pragma unroll
      for (int jj = 0; jj < 8; jj++) {
        int n = kk + kc * 8 + jj;
        float bmu = (float)(n >> 1) * (1.f / 511.f);
        int p = jj & 1;  // parity of n (kk, kc*8 even)
        float tt = (bmu - m_) * ivs[p];
        float v = cof[p] * __expf(-0.5f * tt * tt);
        short hb = f2bf(v);
        hv[jj] = hb;
        lv[jj] = f2bf(v - bf2f(hb));
      }
      lAh[b][cidx] = hv;
      lAl[b][cidx] = lv;
    }
  };
  f32x4 acc[4];
  const f32x4 z = {0.f, 0.f, 0.f, 0.f};
#pragma unroll
  for (int j = 0; j < 4; j++) acc[j] = z;
  stageB(0, 0);
  stageA(0, 0);
  __syncthreads();
  int cur = 0;
  for (int k0 = 0; k0 < kNB; k0 += 32) {
    if (k0 + 32 < kNB) {
      stageB(cur ^ 1, k0 + 32);   // async loads issued first
      stageA(cur ^ 1, k0 + 32);   // VALU generation overlaps their latency
    }
    s16x8 ah, al, bh[4], bl[4];
    ah = lAh[cur][wm * 64 + lane];
    al = lAl[cur][wm * 64 + lane];
#pragma unroll
    for (int j = 0; j < 4; j++) {
      bh[j] = lBh[cur][(wn * 4 + j) * 64 + lane];
      bl[j] = lBl[cur][(wn * 4 + j) * 64 + lane];
    }
#pragma unroll
    for (int j = 0; j < 4; j++) {
      acc[j] = __builtin_amdgcn_mfma_f32_16x16x32_bf16(ah, bh[j], acc[j], 0, 0, 0);
      acc[j] = __builtin_amdgcn_mfma_f32_16x16x32_bf16(ah, bl[j], acc[j], 0, 0, 0);
      acc[j] = __builtin_amdgcn_mfma_f32_16x16x32_bf16(al, bh[j], acc[j], 0, 0, 0);
    }
    __syncthreads();
    cur ^= 1;
  }
  short* Cp = ctx + h * kD;
#pragma unroll
  for (int j = 0; j < 4; j++) {
    int gn = (wn * 4 + j) * 16 + l16;
#pragma unroll
    for (int rg = 0; rg < 4; rg++) {
      int gm = m0 + wm * 16 + quad * 4 + rg;
      Cp[(long long)gm * kDM + gn] = f2bf(acc[j][rg]);
    }
  }
}

extern "C" void kernel_launch(void* const* d_in, const int* in_sizes, int n_in,
                              void* d_out, int out_size, void* d_ws, size_t ws_size,
                              hipStream_t stream) {
  (void)in_sizes; (void)n_in; (void)out_size; (void)ws_size;
  const void* kmem = d_in[0];
  const void* q    = d_in[1];
  const void* Wk   = d_in[2];
  const void* Wv   = d_in[3];
  const void* Wo   = d_in[4];
  const void* wmu  = d_in[5];
  const void* wsg  = d_in[6];

  // ---- workspace layout (~32.5 MB total) ----
  char* ws = (char*)d_ws;
  short* k_bf  = (short*)ws;                          // [512][2048] bf16, 2 MB
  short* kvT   = (short*)(ws + ((size_t)2 << 20));    // [2048][512] bf16, 2 MB
  short* Wv_bf = (short*)(ws + ((size_t)4 << 20));    // [2048][2048] bf16, 8 MB (dead after kv)
  short* Wo_bf = Wv_bf;                               // overlay AFTER kv GEMM
  float* Pbuf  = (float*)(ws + ((size_t)12 << 20));   // [4][512][2048] f32, 16 MB (kv partials; dead after reduce)
  short* VTh   = (short*)(ws + ((size_t)12 << 20));   // [2048][1024] bf16, 4 MB (overlays Pbuf)
  short* VTl   = (short*)(ws + ((size_t)16 << 20));   // [2048][1024] bf16, 4 MB
  short* ctx   = (short*)(ws + ((size_t)20 << 20));   // [2048][2048] bf16, 8 MB
  float* tail  = (float*)(ws + ((size_t)28 << 20));
  float* gw    = tail;                 // 2*512
  float* bw    = gw + 2 * kML;         // 2*2048
  float* kw    = bw + 2 * kDM;         // 2*2048
  float* mu    = kw + 2 * kDM;         // 16*2048
  float* sigsq = mu + kH * kQL;        // 16*2048
  int*   flag  = (int*)(sigsq + kH * kQL);
  float* gtffall = (float*)(ws + ((size_t)28 << 20) + ((size_t)1 << 19));  // 2 MB @28.5
  short* ghfall  = (short*)(ws + ((size_t)30 << 20) + ((size_t)1 << 19));  // 1 MB @30.5
  short* glfall  = (short*)(ws + ((size_t)31 << 20) + ((size_t)1 << 19));  // 1 MB @31.5

  const float* GtTf = g_init.d_GtTf;
  if (!GtTf) {
    const void* src = g_init.h_GtTf_pinned ? (const void*)g_init.h_GtTf_pinned
                                           : (const void*)g_init.h_GtTf.data();
    hipMemcpyAsync(gtffall, src, (size_t)kNB * kML * 4, hipMemcpyHostToDevice, stream);
    GtTf = gtffall;
  }
  const short* Gh = (const short*)g_init.d_Gth;
  if (!Gh) {
    const void* src = g_init.h_Gth_pinned ? (const void*)g_init.h_Gth_pinned
                                          : (const void*)g_init.h_Gth.data();
    hipMemcpyAsync(ghfall, src, (size_t)kNB * kML * 2, hipMemcpyHostToDevice, stream);
    Gh = ghfall;
  }
  const short* Gl = (const short*)g_init.d_Gtl;
  if (!Gl) {
    const void* src = g_init.h_Gtl_pinned ? (const void*)g_init.h_Gtl_pinned
                                          : (const void*)g_init.h_Gtl.data();
    hipMemcpyAsync(glfall, src, (size_t)kNB * kML * 2, hipMemcpyHostToDevice, stream);
    Gl = glfall;
  }

  // 0) dtype flag
  detect_kernel<<<1, 256, 0, stream>>>((const unsigned short*)q, flag);

  // prep: k, Wv -> bf16
  conv_bf16<<<(kML * kDM / 4 + 255) / 256, 256, 0, stream>>>(kmem, k_bf, kML * kDM / 4, flag);
  conv_bf16<<<(kDM * kDM / 4 + 255) / 256, 256, 0, stream>>>(Wv, Wv_bf, kDM * kDM / 4, flag);

  // exact f32 mu/sigma path (parallelized: 512-block gw, 128-block bwk)
  gw_kernel<<<kML, 256, 0, stream>>>(GtTf, wmu, wsg, gw, flag);
  hipMemsetAsync(bw, 0, 2 * kDM * sizeof(float), stream);
  bwk_kernel<<<dim3(kDM / 256, kML / 32), 256, 0, stream>>>(kmem, gw, bw, flag);
  kw_kernel<<<kDM, 256, 0, stream>>>(Wk, bw, kw, flag);
  musig_kernel<<<kH * kQL / 4, 256, 0, stream>>>(q, kw, mu, sigsq, flag);

  // kv GEMM split-K=4: P[z][l][d] partials. 64x64 tiles -> 1024 blocks (4/CU).
  mfma_gemm_sk<<<dim3(kDM / 64, kML / 64, 4), 256, 0, stream>>>(
      k_bf, kDM, Wv_bf, kDM, Pbuf, kDM);
  // reduce partials -> kvT[d][l] bf16 (single f2bf rounding, as before)
  reduceT_kernel<<<dim3(kDM / 64, kML / 64), 256, 0, stream>>>(Pbuf, kvT);

  // Wo -> bf16 (overlays Wv_bf, dead after kv GEMM)
  conv_bf16<<<(kDM * kDM / 4 + 255) / 256, 256, 0, stream>>>(Wo, Wo_bf, kDM * kDM / 4, flag);

  // valuesT[d][n] = sum_l kvT[d][l] * G[l][n]  (split G in, split VT out)
  // 64x64 tiles -> grid (16 n, 32 d) = 512 blocks (2/CU).
  mfma_gemm_bt2<<<dim3(kNB / 64, kDM / 64, 1), 256, 0, stream>>>(
      kvT, kML, Gh, Gl, kML, VTh, VTl, kNB, kML);

  // ctx[q][h*128+d'] = sum_n r(h,q,n) * valuesT[h*128+d'][n]  (3-pass split x split)
  // 32-row q-tiles -> grid (1, 64, 16) = 1024 blocks (4/CU).
  mfma_rv<<<dim3(1, kQL / 32, kH), 256, 0, stream>>>(mu, sigsq, VTh, VTl, ctx);

  // out = ctx @ Wo^T  (runtime out dtype). 64x64 tiles -> grid (32, 32) = 1024.
  mfma_gemm_bt<2><<<dim3(kDM / 64, kQL / 64, 1), 256, 0, stream>>>(
      ctx, kDM, 0, Wo_bf, kDM, 0, d_out, kDM, 0, kDM, flag);
}

// Round 11
// 268.217 us; speedup vs baseline: 1.1826x; 1.1826x over previous
//
#include <hip/hip_runtime.h>
#include <hip/hip_bf16.h>
#include <vector>
#include <cmath>
#include <cstring>

using bf16 = __hip_bfloat16;
typedef short s16x8 __attribute__((ext_vector_type(8)));
typedef float f32x4 __attribute__((ext_vector_type(4)));

static constexpr int kH = 16, kD = 128, kNB = 1024, kML = 512, kQL = 2048, kDM = 2048;

// counted-vmcnt barrier (m201 pattern)
#define VMB(N) do { asm volatile("s_waitcnt vmcnt(" #N ")" ::: "memory"); \
                    __builtin_amdgcn_s_barrier(); \
                    asm volatile("" ::: "memory"); } while (0)
#define VMLB(N) do { asm volatile("s_waitcnt vmcnt(" #N ") lgkmcnt(0)" ::: "memory"); \
                     __builtin_amdgcn_s_barrier(); \
                     asm volatile("" ::: "memory"); } while (0)
// bank-conflict swizzle for VALU-staged (ds_write) LDS tiles; involution,
// applied identically on write and read. NOT used on global_load_lds tiles.
#define SWZ(c) ((c) ^ (((c) >> 4) & 3))

// ================= host precompute of Gt (input-independent) =================
static void compute_Gt_host(float* Gt) {
  const int n = kNB, P = 2 * kML;
  std::vector<double> F((size_t)n * P), A((size_t)n * n), pos(P);
  const double shift = 1.0 / (double)P;
  const double p0 = -0.5 + shift, p1 = 1.5 - shift;
  for (int i = 0; i < P; i++) pos[i] = p0 + (p1 - p0) * (double)i / (double)(P - 1);
  const double c0 = 0.3989422804014327;
  std::vector<int> lo(n), hi(n);
  for (int b = 0; b < n; b++) {
    double mu = (double)(b >> 1) / 511.0;
    double sg = (b & 1) ? 0.01 : 0.005;
    double c = c0 / sg;
    double* Fb = &F[(size_t)b * P];
    for (int i = 0; i < P; i++) { double t = (pos[i] - mu) / sg; Fb[i] = c * exp(-0.5 * t * t); }
    int l = 0; while (l < P - 1 && pos[l] < mu - 14.0 * sg) l++;
    int h = P - 1; while (h > 0 && pos[h] > mu + 14.0 * sg) h--;
    lo[b] = l; hi[b] = h;
  }
  for (int i = 0; i < n; i++) {
    const double* fi = &F[(size_t)i * P];
    for (int j = 0; j <= i; j++) {
      const double* fj = &F[(size_t)j * P];
      int a = lo[i] > lo[j] ? lo[i] : lo[j];
      int b2 = hi[i] < hi[j] ? hi[i] : hi[j];
      double s = 0.0;
      for (int k2 = a; k2 <= b2; k2++) s += fi[k2] * fj[k2];
      A[(size_t)i * n + j] = s;
      if (i != j) A[(size_t)j * n + i] = s;
    }
    A[(size_t)i * n + i] += 0.5;
  }
  for (int j = 0; j < n; j++) {  // Cholesky
    double* Aj = &A[(size_t)j * n];
    double d = Aj[j];
    for (int k2 = 0; k2 < j; k2++) d -= Aj[k2] * Aj[k2];
    d = std::sqrt(d); Aj[j] = d;
    double inv = 1.0 / d;
    for (int i = j + 1; i < n; i++) {
      double* Ai = &A[(size_t)i * n];
      double s = Ai[j];
      for (int k2 = 0; k2 < j; k2++) s -= Ai[k2] * Aj[k2];
      Ai[j] = s * inv;
    }
  }
  for (int i = 0; i < n; i++) {  // L Y = F
    double* yi = &F[(size_t)i * P];
    const double* Ai = &A[(size_t)i * n];
    for (int k2 = 0; k2 < i; k2++) {
      double lik = Ai[k2];
      const double* yk = &F[(size_t)k2 * P];
      for (int t = 0; t < P; t++) yi[t] -= lik * yk[t];
    }
    double inv = 1.0 / Ai[i];
    for (int t = 0; t < P; t++) yi[t] *= inv;
  }
  for (int i = n - 1; i >= 0; i--) {  // L^T X = Y
    double* xi = &F[(size_t)i * P];
    for (int k2 = i + 1; k2 < n; k2++) {
      double lki = A[(size_t)k2 * n + i];
      const double* xk = &F[(size_t)k2 * P];
      for (int t = 0; t < P; t++) xi[t] -= lki * xk[t];
    }
    double inv = 1.0 / A[(size_t)i * n + i];
    for (int t = 0; t < P; t++) xi[t] *= inv;
  }
  for (int b = 0; b < n; b++)
    for (int l = 0; l < kML; l++)
      Gt[(size_t)b * kML + l] = (float)F[(size_t)b * P + (kML / 2) + l];
}

static unsigned short f2bf_host(float x) {
  unsigned u; std::memcpy(&u, &x, 4);
  unsigned r = (u + 0x7FFFu + ((u >> 16) & 1u)) >> 16;
  return (unsigned short)r;
}
static float bf2f_host(unsigned short b) {
  unsigned u = ((unsigned)b) << 16; float f; std::memcpy(&f, &u, 4); return f;
}

namespace {
struct Init {
  float* d_GtTf = nullptr;           // f32 GtT[l][n]  [512][1024]
  unsigned short* d_Gth = nullptr;   // bf16-hi Gt[n][l]  [1024][512]
  unsigned short* d_Gtl = nullptr;   // bf16-lo Gt[n][l]  [1024][512]
  float* h_GtTf_pinned = nullptr;
  unsigned short* h_Gth_pinned = nullptr;
  unsigned short* h_Gtl_pinned = nullptr;
  std::vector<float> h_GtTf;
  std::vector<unsigned short> h_Gth, h_Gtl;
  Init() {
    std::vector<float> h_Gt((size_t)kNB * kML);
    compute_Gt_host(h_Gt.data());
    h_GtTf.resize(h_Gt.size());
    h_Gth.resize(h_Gt.size());
    h_Gtl.resize(h_Gt.size());
    for (int n = 0; n < kNB; n++)
      for (int l = 0; l < kML; l++) {
        float v = h_Gt[(size_t)n * kML + l];
        h_GtTf[(size_t)l * kNB + n] = v;
        unsigned short hb = f2bf_host(v);
        h_Gth[(size_t)n * kML + l] = hb;
        h_Gtl[(size_t)n * kML + l] = f2bf_host(v - bf2f_host(hb));
      }
    const size_t fb = h_Gt.size() * 4, bb = h_Gt.size() * 2;
    if (hipMalloc((void**)&d_GtTf, fb) == hipSuccess) {
      if (hipMemcpy(d_GtTf, h_GtTf.data(), fb, hipMemcpyHostToDevice) != hipSuccess) { hipFree(d_GtTf); d_GtTf = nullptr; }
    }
    if (hipMalloc((void**)&d_Gth, bb) == hipSuccess) {
      if (hipMemcpy(d_Gth, h_Gth.data(), bb, hipMemcpyHostToDevice) != hipSuccess) { hipFree(d_Gth); d_Gth = nullptr; }
    }
    if (hipMalloc((void**)&d_Gtl, bb) == hipSuccess) {
      if (hipMemcpy(d_Gtl, h_Gtl.data(), bb, hipMemcpyHostToDevice) != hipSuccess) { hipFree(d_Gtl); d_Gtl = nullptr; }
    }
    if (!d_GtTf && hipHostMalloc((void**)&h_GtTf_pinned, fb, 0) == hipSuccess)
      std::memcpy(h_GtTf_pinned, h_GtTf.data(), fb);
    if (!d_Gth && hipHostMalloc((void**)&h_Gth_pinned, bb, 0) == hipSuccess)
      std::memcpy(h_Gth_pinned, h_Gth.data(), bb);
    if (!d_Gtl && hipHostMalloc((void**)&h_Gtl_pinned, bb, 0) == hipSuccess)
      std::memcpy(h_Gtl_pinned, h_Gtl.data(), bb);
  }
};
Init g_init;
}

// ================= device helpers =================
__device__ inline short f2bf(float x) {
  unsigned u = __float_as_uint(x);
  unsigned r = (u + 0x7FFFu + ((u >> 16) & 1u)) >> 16;
  return (short)r;
}
__device__ inline float bf2f(short b) {
  return __uint_as_float(((unsigned)(unsigned short)b) << 16);
}

// async global->LDS, 16 B per lane; LDS dest is wave-uniform base + lane*16.
__device__ inline void gload16(const void* g, void* l) {
  __builtin_amdgcn_global_load_lds(
      (__attribute__((address_space(1))) void*)(g),
      (__attribute__((address_space(3))) void*)(l),
      16, 0, 0);
}

// ================= dtype detection =================
__global__ __launch_bounds__(256) void detect_kernel(const unsigned short* __restrict__ q,
                                                     int* __restrict__ flag) {
  int t = threadIdx.x;
  int bad = 0;
  for (int i = t; i < 4096; i += 256) {
    int e = (q[i] >> 7) & 0xFF;
    if (e >= 0x98) bad = 1;
  }
  __shared__ int s[256];
  s[t] = bad; __syncthreads();
  for (int k2 = 128; k2 > 0; k2 >>= 1) { if (t < k2) s[t] |= s[t + k2]; __syncthreads(); }
  if (t == 0) *flag = s[0];  // 1 => float32 inputs
}

// elementwise convert (f32|bf16 in) -> bf16, 4 elems/thread
__global__ __launch_bounds__(256) void conv_bf16(const void* __restrict__ in,
                                                 short* __restrict__ out, int n4,
                                                 const int* __restrict__ flag) {
  int i = blockIdx.x * 256 + threadIdx.x;
  if (i >= n4) return;
  if (*flag) {
    float4 v = ((const float4*)in)[i];
    short4 o; o.x = f2bf(v.x); o.y = f2bf(v.y); o.z = f2bf(v.z); o.w = f2bf(v.w);
    ((short4*)out)[i] = o;
  } else {
    ((short4*)out)[i] = ((const short4*)in)[i];
  }
}

// ===== exact f32 mu/sigma path =====
__global__ __launch_bounds__(256) void gw_kernel(const float* __restrict__ GtT,
                                                 const void* __restrict__ wmu,
                                                 const void* __restrict__ wsg,
                                                 float* __restrict__ gw,
                                                 const int* __restrict__ flag) {
  const bool f32 = (*flag != 0);
  const int l = blockIdx.x, t = threadIdx.x;
  const float* row = GtT + (long long)l * kNB;
  float a = 0.f, b = 0.f;
  for (int n = t; n < kNB; n += 256) {
    float g = row[n];
    float wm_ = f32 ? ((const float*)wmu)[n] : bf2f(((const short*)wmu)[n]);
    float ws_ = f32 ? ((const float*)wsg)[n] : bf2f(((const short*)wsg)[n]);
    a += g * wm_; b += g * ws_;
  }
  __shared__ float red[2][256];
  red[0][t] = a; red[1][t] = b;
  __syncthreads();
  for (int s = 128; s > 0; s >>= 1) {
    if (t < s) { red[0][t] += red[0][t + s]; red[1][t] += red[1][t + s]; }
    __syncthreads();
  }
  if (t == 0) { gw[l] = red[0][0]; gw[kML + l] = red[1][0]; }
}

__global__ __launch_bounds__(256) void bwk_kernel(const void* __restrict__ kin,
                                                  const float* __restrict__ gw,
                                                  float* __restrict__ bw,
                                                  const int* __restrict__ flag) {
  const bool f32 = (*flag != 0);
  int j = blockIdx.x * 256 + threadIdx.x;
  int l0 = blockIdx.y * 32;
  float a = 0.f, b = 0.f;
  for (int l = l0; l < l0 + 32; l++) {
    float kv = f32 ? ((const float*)kin)[(long long)l * kDM + j]
                   : bf2f(((const short*)kin)[(long long)l * kDM + j]);
    a += kv * gw[l]; b += kv * gw[kML + l];
  }
  atomicAdd(&bw[j], a);
  atomicAdd(&bw[kDM + j], b);
}

__global__ __launch_bounds__(256) void kw_kernel(const void* __restrict__ Wk,
                                                 const float* __restrict__ bw,
                                                 float* __restrict__ kw,
                                                 const int* __restrict__ flag) {
  const bool f32 = (*flag != 0);
  int i = blockIdx.x;
  float smu = 0.f, ssg = 0.f;
  if (f32) {
    const float* row = (const float*)Wk + (long long)i * kDM;
    for (int j = threadIdx.x; j < kDM; j += 256) { float w = row[j]; smu += w * bw[j]; ssg += w * bw[kDM + j]; }
  } else {
    const short* row = (const short*)Wk + (long long)i * kDM;
    for (int j = threadIdx.x; j < kDM; j += 256) { float w = bf2f(row[j]); smu += w * bw[j]; ssg += w * bw[kDM + j]; }
  }
  __shared__ float red[2][256];
  red[0][threadIdx.x] = smu; red[1][threadIdx.x] = ssg;
  __syncthreads();
  for (int s = 128; s > 0; s >>= 1) {
    if (threadIdx.x < (unsigned)s) {
      red[0][threadIdx.x] += red[0][threadIdx.x + s];
      red[1][threadIdx.x] += red[1][threadIdx.x + s];
    }
    __syncthreads();
  }
  if (threadIdx.x == 0) { kw[i] = red[0][0]; kw[kDM + i] = red[1][0]; }
}

__global__ __launch_bounds__(256) void musig_kernel(const void* __restrict__ q,
                                                    const float* __restrict__ kw,
                                                    float* __restrict__ mu,
                                                    float* __restrict__ sigsq,
                                                    const int* __restrict__ flag) {
  const bool f32 = (*flag != 0);
  int w = threadIdx.x >> 6, lane = threadIdx.x & 63;
  int idx = blockIdx.x * 4 + w;  // h*2048 + q
  int h = idx >> 11;
  const float* kmu = kw + h * kD;
  const float* ksg = kw + kDM + h * kD;
  float q0, q1;
  if (f32) {
    const float* qrow = (const float*)q + (long long)idx * kD;
    q0 = qrow[lane]; q1 = qrow[lane + 64];
  } else {
    const short* qrow = (const short*)q + (long long)idx * kD;
    q0 = bf2f(qrow[lane]); q1 = bf2f(qrow[lane + 64]);
  }
  float a = q0 * kmu[lane] + q1 * kmu[lane + 64];
  float b = q0 * ksg[lane] + q1 * ksg[lane + 64];
  for (int s = 32; s > 0; s >>= 1) { a += __shfl_xor(a, s); b += __shfl_xor(b, s); }
  if (lane == 0) {
    const float inv_sqrt_d = 0.08838834764831845f;
    float zm = a * inv_sqrt_d, zs = b * inv_sqrt_d;
    mu[idx] = 1.f / (1.f + __expf(-zm));
    float sp = (zs > 20.f) ? zs : log1pf(__expf(zs));
    sigsq[idx] = fmaxf(sp, 1e-4f);
  }
}

// ===== MFMA GEMM: C[M,N] = A[M,K] @ BT[N,K]^T (bf16 in, f32 acc) ===============
// Tile 128x64, BK=64. 3-buffer pipeline, prefetch distance 2, counted vmcnt(6).
// MFMA K-order unchanged -> bit-identical C. LDS 72 KB -> 2 blocks/CU (grid 512).
// CSTORE: 0 = bf16; 2 = runtime dtype.
template <int CSTORE>
__global__ __launch_bounds__(256) void mfma_gemm_bt(
    const short* __restrict__ A0, int lda, long long sA,
    const short* __restrict__ BT0, int ldb, long long sB,
    void* __restrict__ C0, int ldc, long long sC,
    int K, const int* __restrict__ flag) {
  __shared__ s16x8 lA[3][1024];  // [buf][ks*512 + sub*64 + lane]
  __shared__ s16x8 lB[3][512];   // [buf][ks*256 + sub*64 + lane]
  const short* A = A0 + (long long)blockIdx.z * sA;
  const short* BT = BT0 + (long long)blockIdx.z * sB;
  const int t = threadIdx.x;
  const int wave = t >> 6, lane = t & 63;
  const int quad = lane >> 4, l16 = lane & 15;
  const int wm = wave >> 1, wn = wave & 1;
  const int m0 = blockIdx.y * 128, n0 = blockIdx.x * 64;
  const int srow = lane & 15, skc = lane >> 4;
  auto stage = [&](int b, int kk) {              // 6 gload16 per lane
#pragma unroll
    for (int i = 0; i < 2; i++) {
      int sub = wave + i * 4;         // A subtiles 0..7
      int m = sub * 16 + srow;
#pragma unroll
      for (int ks = 0; ks < 2; ks++)
        gload16(A + (long long)(m0 + m) * lda + kk + ks * 32 + skc * 8,
                &lA[b][ks * 512 + sub * 64]);
    }
    int mB = wave * 16 + srow;        // B subtiles 0..3, one per wave
#pragma unroll
    for (int ks = 0; ks < 2; ks++)
      gload16(BT + (long long)(n0 + mB) * ldb + kk + ks * 32 + skc * 8,
              &lB[b][ks * 256 + wave * 64]);
  };
  f32x4 acc[4][2];
  const f32x4 z = {0.f, 0.f, 0.f, 0.f};
#pragma unroll
  for (int i = 0; i < 4; i++)
#pragma unroll
    for (int j = 0; j < 2; j++) acc[i][j] = z;
  stage(0, 0);
  stage(1, 64);
  VMB(6);                       // tile 0 landed; tile 1 in flight
  const int NT = K >> 6;
  int cur = 0, pf = 2;
  for (int tt = 0; tt < NT; ++tt) {
    const bool more = (tt + 2 < NT);
    if (more) stage(pf, (tt + 2) << 6);
#pragma unroll
    for (int ks = 0; ks < 2; ks++) {
      s16x8 af[4], bfr[2];
#pragma unroll
      for (int i = 0; i < 4; i++) af[i] = lA[cur][ks * 512 + (wm * 4 + i) * 64 + lane];
#pragma unroll
      for (int j = 0; j < 2; j++) bfr[j] = lB[cur][ks * 256 + (wn * 2 + j) * 64 + lane];
#pragma unroll
      for (int i = 0; i < 4; i++)
#pragma unroll
        for (int j = 0; j < 2; j++)
          acc[i][j] = __builtin_amdgcn_mfma_f32_16x16x32_bf16(af[i], bfr[j], acc[i][j], 0, 0, 0);
    }
    if (more) VMB(6); else VMB(0);
    cur = (cur == 2) ? 0 : cur + 1;
    pf = (pf == 2) ? 0 : pf + 1;
  }
  // epilogue: C/D layout col=lane&15, row=quad*4+reg
  if (CSTORE == 0) {
    short* Cp = (short*)C0 + (long long)blockIdx.z * sC;
#pragma unroll
    for (int i = 0; i < 4; i++)
#pragma unroll
      for (int j = 0; j < 2; j++) {
        int gn = n0 + (wn * 2 + j) * 16 + l16;
#pragma unroll
        for (int rg = 0; rg < 4; rg++) {
          int gm = m0 + (wm * 4 + i) * 16 + quad * 4 + rg;
          Cp[(long long)gm * ldc + gn] = f2bf(acc[i][j][rg]);
        }
      }
  } else {
    if (*flag) {
      float* Cp = (float*)C0 + (long long)blockIdx.z * sC;
#pragma unroll
      for (int i = 0; i < 4; i++)
#pragma unroll
        for (int j = 0; j < 2; j++) {
          int gn = n0 + (wn * 2 + j) * 16 + l16;
#pragma unroll
          for (int rg = 0; rg < 4; rg++) {
            int gm = m0 + (wm * 4 + i) * 16 + quad * 4 + rg;
            Cp[(long long)gm * ldc + gn] = acc[i][j][rg];
          }
        }
    } else {
      short* Cp = (short*)C0 + (long long)blockIdx.z * sC;
#pragma unroll
      for (int i = 0; i < 4; i++)
#pragma unroll
        for (int j = 0; j < 2; j++) {
          int gn = n0 + (wn * 2 + j) * 16 + l16;
#pragma unroll
          for (int rg = 0; rg < 4; rg++) {
            int gm = m0 + (wm * 4 + i) * 16 + quad * 4 + rg;
            Cp[(long long)gm * ldc + gn] = f2bf(acc[i][j][rg]);
          }
        }
    }
  }
}

// ===== split-K kv GEMM: P[z][l][d] = k[l][:] @ Wv[d][:] over K-chunk z ========
// Tile 128x64, BK=64, 3-buffer counted-vmcnt pipeline (as bt). Grid 512 blocks.
__global__ __launch_bounds__(256) void mfma_gemm_sk(
    const short* __restrict__ A0, int lda,      // k_bf [512][2048]
    const short* __restrict__ BT0, int ldb,     // Wv_bf [2048][2048]
    float* __restrict__ P, int ldc) {           // [4][512][2048] f32
  __shared__ s16x8 lA[3][1024], lB[3][512];  // 72 KB
  const int t = threadIdx.x;
  const int wave = t >> 6, lane = t & 63;
  const int quad = lane >> 4, l16 = lane & 15;
  const int wm = wave >> 1, wn = wave & 1;
  const int m0 = blockIdx.y * 128, n0 = blockIdx.x * 64;
  const int kbeg = blockIdx.z * 512;
  const int srow = lane & 15, skc = lane >> 4;
  auto stage = [&](int b, int kk) {  // 6 gload16 per lane
#pragma unroll
    for (int i = 0; i < 2; i++) {
      int sub = wave + i * 4;
      int m = sub * 16 + srow;
#pragma unroll
      for (int ks = 0; ks < 2; ks++)
        gload16(A0 + (long long)(m0 + m) * lda + kk + ks * 32 + skc * 8,
                &lA[b][ks * 512 + sub * 64]);
    }
    int mB = wave * 16 + srow;
#pragma unroll
    for (int ks = 0; ks < 2; ks++)
      gload16(BT0 + (long long)(n0 + mB) * ldb + kk + ks * 32 + skc * 8,
              &lB[b][ks * 256 + wave * 64]);
  };
  f32x4 acc[4][2];
  const f32x4 z = {0.f, 0.f, 0.f, 0.f};
#pragma unroll
  for (int i = 0; i < 4; i++)
#pragma unroll
    for (int j = 0; j < 2; j++) acc[i][j] = z;
  stage(0, kbeg);
  stage(1, kbeg + 64);
  VMB(6);
  const int NT = 8;  // 512/64
  int cur = 0, pf = 2;
  for (int tt = 0; tt < NT; ++tt) {
    const bool more = (tt + 2 < NT);
    if (more) stage(pf, kbeg + ((tt + 2) << 6));
#pragma unroll
    for (int ks = 0; ks < 2; ks++) {
      s16x8 af[4], bfr[2];
#pragma unroll
      for (int i = 0; i < 4; i++) af[i] = lA[cur][ks * 512 + (wm * 4 + i) * 64 + lane];
#pragma unroll
      for (int j = 0; j < 2; j++) bfr[j] = lB[cur][ks * 256 + (wn * 2 + j) * 64 + lane];
#pragma unroll
      for (int i = 0; i < 4; i++)
#pragma unroll
        for (int j = 0; j < 2; j++)
          acc[i][j] = __builtin_amdgcn_mfma_f32_16x16x32_bf16(af[i], bfr[j], acc[i][j], 0, 0, 0);
    }
    if (more) VMB(6); else VMB(0);
    cur = (cur == 2) ? 0 : cur + 1;
    pf = (pf == 2) ? 0 : pf + 1;
  }
  float* Cp = P + (long long)blockIdx.z * kML * kDM;
#pragma unroll
  for (int i = 0; i < 4; i++)
#pragma unroll
    for (int j = 0; j < 2; j++) {
      int gn = n0 + (wn * 2 + j) * 16 + l16;
#pragma unroll
      for (int rg = 0; rg < 4; rg++) {
        int gm = m0 + (wm * 4 + i) * 16 + quad * 4 + rg;
        Cp[(long long)gm * ldc + gn] = acc[i][j][rg];
      }
    }
}

// reduce 4 f32 partials [z][l][d] -> kvT bf16 [d][l] (LDS transpose)
__global__ __launch_bounds__(256) void reduceT_kernel(const float* __restrict__ P,
                                                      short* __restrict__ kvT) {
  __shared__ float tile[64][65];
  const int bd = blockIdx.x, bl = blockIdx.y;  // 32 x 8
  const int tx = threadIdx.x & 63, ty = threadIdx.x >> 6;
  for (int i = ty; i < 64; i += 4) {
    int l = bl * 64 + i, d = bd * 64 + tx;
    float s = 0.f;
#pragma unroll
    for (int z = 0; z < 4; z++) s += P[((long long)z * kML + l) * kDM + d];
    tile[i][tx] = s;
  }
  __syncthreads();
  for (int i = ty; i < 64; i += 4) {
    int d = bd * 64 + i, l = bl * 64 + tx;
    kvT[(long long)d * kML + l] = f2bf(tile[tx][i]);
  }
}

// ===== split-B GEMM with SPLIT OUTPUT ==========================================
// Tile 64x64, BK=32, 3-buffer counted-vmcnt(3) pipeline. Grid 512. LDS 36 KB.
__global__ __launch_bounds__(256) void mfma_gemm_bt2(
    const short* __restrict__ A0, int lda,
    const short* __restrict__ BTh, const short* __restrict__ BTl, int ldb,
    short* __restrict__ Ch, short* __restrict__ Cl, int ldc, int K) {
  __shared__ s16x8 lA[3][256], lBh[3][256], lBl[3][256];  // 36 KB
  const int t = threadIdx.x;
  const int wave = t >> 6, lane = t & 63;
  const int quad = lane >> 4, l16 = lane & 15;
  const int wm = wave >> 1, wn = wave & 1;
  const int m0 = blockIdx.y * 64, n0 = blockIdx.x * 64;
  const int srow = lane & 15, skc = lane >> 4;
  auto stage = [&](int b, int kk) {  // 3 gload16 per lane
    int m = wave * 16 + srow;
    gload16(A0 + (long long)(m0 + m) * lda + kk + skc * 8, &lA[b][wave * 64]);
    gload16(BTh + (long long)(n0 + m) * ldb + kk + skc * 8, &lBh[b][wave * 64]);
    gload16(BTl + (long long)(n0 + m) * ldb + kk + skc * 8, &lBl[b][wave * 64]);
  };
  f32x4 acc[2][2];
  const f32x4 z = {0.f, 0.f, 0.f, 0.f};
#pragma unroll
  for (int i = 0; i < 2; i++)
#pragma unroll
    for (int j = 0; j < 2; j++) acc[i][j] = z;
  stage(0, 0);
  stage(1, 32);
  VMB(3);
  const int NT = K >> 5;
  int cur = 0, pf = 2;
  for (int tt = 0; tt < NT; ++tt) {
    const bool more = (tt + 2 < NT);
    if (more) stage(pf, (tt + 2) << 5);
    s16x8 af[2], bh[2], bl[2];
#pragma unroll
    for (int i = 0; i < 2; i++) af[i] = lA[cur][(wm * 2 + i) * 64 + lane];
#pragma unroll
    for (int j = 0; j < 2; j++) {
      bh[j] = lBh[cur][(wn * 2 + j) * 64 + lane];
      bl[j] = lBl[cur][(wn * 2 + j) * 64 + lane];
    }
#pragma unroll
    for (int i = 0; i < 2; i++)
#pragma unroll
      for (int j = 0; j < 2; j++) {
        acc[i][j] = __builtin_amdgcn_mfma_f32_16x16x32_bf16(af[i], bh[j], acc[i][j], 0, 0, 0);
        acc[i][j] = __builtin_amdgcn_mfma_f32_16x16x32_bf16(af[i], bl[j], acc[i][j], 0, 0, 0);
      }
    if (more) VMB(3); else VMB(0);
    cur = (cur == 2) ? 0 : cur + 1;
    pf = (pf == 2) ? 0 : pf + 1;
  }
#pragma unroll
  for (int i = 0; i < 2; i++)
#pragma unroll
    for (int j = 0; j < 2; j++) {
      int gn = n0 + (wn * 2 + j) * 16 + l16;
#pragma unroll
      for (int rg = 0; rg < 4; rg++) {
        int gm = m0 + (wm * 2 + i) * 16 + quad * 4 + rg;
        float v = acc[i][j][rg];
        short hb = f2bf(v);
        Ch[(long long)gm * ldc + gn] = hb;
        Cl[(long long)gm * ldc + gn] = f2bf(v - bf2f(hb));
      }
    }
}

// ===== fused r-GEMM: ctx[q][h*128+d'] = sum_n r(h,q,n) * valuesT[h*128+d'][n] ===
// Tile 64 q-rows x 128 d-cols, BK=32, 3-buffer pipeline (counted vmcnt(4) +
// lgkmcnt(0)). r generated on the fly (split rh+rl, ds_write staging with
// SWZ bank-conflict swizzle -- lA is VALU-staged so swizzle is legal; lB stays
// linear for global_load_lds). 3 MFMA passes: rh*VTh + rh*VTl + rl*VTh.
// Grid 512. LDS 72 KB.
__global__ __launch_bounds__(256) void mfma_rv(
    const float* __restrict__ mu_all, const float* __restrict__ s2_all,  // [16*2048]
    const short* __restrict__ VTh, const short* __restrict__ VTl,  // [2048][1024]
    short* __restrict__ ctx) {                                     // [2048][2048]
  __shared__ s16x8 lAh[3][256], lAl[3][256], lBh[3][512], lBl[3][512];  // 72 KB
  const int t = threadIdx.x;
  const int wave = t >> 6, lane = t & 63;
  const int quad = lane >> 4, l16 = lane & 15;
  const int wm = wave >> 1, wn = wave & 1;
  const int h = blockIdx.z;
  const int m0 = blockIdx.y * 64;  // q-rows within head
  const int r0 = t >> 2, kc = t & 3;  // r0 in [0,64): one row per thread
  const int srow = lane & 15, skc = lane >> 4;
  const long long voff = (long long)h * kD * kNB;
  const int row = h * kQL + m0 + r0;
  const float m_ = mu_all[row], s2 = s2_all[row];
  float ivs[2], cof[2];
  ivs[0] = rsqrtf(s2 + 2.5e-5f);  // b_sigma = 0.005 (even n)
  ivs[1] = rsqrtf(s2 + 1e-4f);    // b_sigma = 0.01  (odd n)
  cof[0] = 0.3989422804014327f * ivs[0];
  cof[1] = 0.3989422804014327f * ivs[1];
  const int cidx = SWZ((r0 >> 4) * 64 + kc * 16 + (r0 & 15));
  auto stageB = [&](int b, int kk) {  // 4 gload16 per lane
#pragma unroll
    for (int i = 0; i < 2; i++) {
      int sub = wave + i * 4;  // B subtiles 0..7 (128 d-cols)
      int m = sub * 16 + srow;
      gload16(VTh + voff + (long long)m * kNB + kk + skc * 8, &lBh[b][sub * 64]);
      gload16(VTl + voff + (long long)m * kNB + kk + skc * 8, &lBl[b][sub * 64]);
    }
  };
  auto stageA = [&](int b, int kk) {  // 2 ds_write per lane (swizzled slots)
    s16x8 hv, lv;
#pragma unroll
    for (int jj = 0; jj < 8; jj++) {
      int n = kk + kc * 8 + jj;
      float bmu = (float)(n >> 1) * (1.f / 511.f);
      int p = jj & 1;  // parity of n (kk, kc*8 even)
      float tt = (bmu - m_) * ivs[p];
      float v = cof[p] * __expf(-0.5f * tt * tt);
      short hb = f2bf(v);
      hv[jj] = hb;
      lv[jj] = f2bf(v - bf2f(hb));
    }
    lAh[b][cidx] = hv;
    lAl[b][cidx] = lv;
  };
  f32x4 acc[2][4];
  const f32x4 z = {0.f, 0.f, 0.f, 0.f};
#pragma unroll
  for (int i = 0; i < 2; i++)
#pragma unroll
    for (int j = 0; j < 4; j++) acc[i][j] = z;
  stageB(0, 0);
  stageA(0, 0);
  stageB(1, 32);
  stageA(1, 32);
  VMLB(4);
  const int NT = kNB >> 5;  // 32
  int cur = 0, pf = 2;
  for (int tt = 0; tt < NT; ++tt) {
    const bool more = (tt + 2 < NT);
    if (more) {
      stageB(pf, (tt + 2) << 5);   // async loads issued first
      stageA(pf, (tt + 2) << 5);   // ds_writes precede this iter's ds_reads (in-order DS)
    }
    s16x8 ah[2], al[2], bh[4], bl[4];
#pragma unroll
    for (int i = 0; i < 2; i++) {
      ah[i] = lAh[cur][SWZ((wm * 2 + i) * 64 + lane)];
      al[i] = lAl[cur][SWZ((wm * 2 + i) * 64 + lane)];
    }
#pragma unroll
    for (int j = 0; j < 4; j++) {
      bh[j] = lBh[cur][(wn * 4 + j) * 64 + lane];
      bl[j] = lBl[cur][(wn * 4 + j) * 64 + lane];
    }
#pragma unroll
    for (int i = 0; i < 2; i++)
#pragma unroll
      for (int j = 0; j < 4; j++) {
        acc[i][j] = __builtin_amdgcn_mfma_f32_16x16x32_bf16(ah[i], bh[j], acc[i][j], 0, 0, 0);
        acc[i][j] = __builtin_amdgcn_mfma_f32_16x16x32_bf16(ah[i], bl[j], acc[i][j], 0, 0, 0);
        acc[i][j] = __builtin_amdgcn_mfma_f32_16x16x32_bf16(al[i], bh[j], acc[i][j], 0, 0, 0);
      }
    if (more) VMLB(4); else VMLB(0);
    cur = (cur == 2) ? 0 : cur + 1;
    pf = (pf == 2) ? 0 : pf + 1;
  }
  short* Cp = ctx + h * kD;
#pragma unroll
  for (int i = 0; i < 2; i++)
#pragma unroll
    for (int j = 0; j < 4; j++) {
      int gn = (wn * 4 + j) * 16 + l16;
#pragma unroll
      for (int rg = 0; rg < 4; rg++) {
        int gm = m0 + (wm * 2 + i) * 16 + quad * 4 + rg;
        Cp[(long long)gm * kDM + gn] = f2bf(acc[i][j][rg]);
      }
    }
}

extern "C" void kernel_launch(void* const* d_in, const int* in_sizes, int n_in,
                              void* d_out, int out_size, void* d_ws, size_t ws_size,
                              hipStream_t stream) {
  (void)in_sizes; (void)n_in; (void)out_size; (void)ws_size;
  const void* kmem = d_in[0];
  const void* q    = d_in[1];
  const void* Wk   = d_in[2];
  const void* Wv   = d_in[3];
  const void* Wo   = d_in[4];
  const void* wmu  = d_in[5];
  const void* wsg  = d_in[6];

  // ---- workspace layout (~32.5 MB total) ----
  char* ws = (char*)d_ws;
  short* k_bf  = (short*)ws;                          // [512][2048] bf16, 2 MB
  short* kvT   = (short*)(ws + ((size_t)2 << 20));    // [2048][512] bf16, 2 MB
  short* Wv_bf = (short*)(ws + ((size_t)4 << 20));    // [2048][2048] bf16, 8 MB (dead after kv)
  short* Wo_bf = Wv_bf;                               // overlay AFTER kv GEMM
  float* Pbuf  = (float*)(ws + ((size_t)12 << 20));   // [4][512][2048] f32, 16 MB
  short* VTh   = (short*)(ws + ((size_t)12 << 20));   // [2048][1024] bf16, 4 MB (overlays Pbuf)
  short* VTl   = (short*)(ws + ((size_t)16 << 20));   // [2048][1024] bf16, 4 MB
  short* ctx   = (short*)(ws + ((size_t)20 << 20));   // [2048][2048] bf16, 8 MB
  float* tail  = (float*)(ws + ((size_t)28 << 20));
  float* gw    = tail;                 // 2*512
  float* bw    = gw + 2 * kML;         // 2*2048
  float* kw    = bw + 2 * kDM;         // 2*2048
  float* mu    = kw + 2 * kDM;         // 16*2048
  float* sigsq = mu + kH * kQL;        // 16*2048
  int*   flag  = (int*)(sigsq + kH * kQL);
  float* gtffall = (float*)(ws + ((size_t)28 << 20) + ((size_t)1 << 19));  // 2 MB @28.5
  short* ghfall  = (short*)(ws + ((size_t)30 << 20) + ((size_t)1 << 19));  // 1 MB @30.5
  short* glfall  = (short*)(ws + ((size_t)31 << 20) + ((size_t)1 << 19));  // 1 MB @31.5

  const float* GtTf = g_init.d_GtTf;
  if (!GtTf) {
    const void* src = g_init.h_GtTf_pinned ? (const void*)g_init.h_GtTf_pinned
                                           : (const void*)g_init.h_GtTf.data();
    hipMemcpyAsync(gtffall, src, (size_t)kNB * kML * 4, hipMemcpyHostToDevice, stream);
    GtTf = gtffall;
  }
  const short* Gh = (const short*)g_init.d_Gth;
  if (!Gh) {
    const void* src = g_init.h_Gth_pinned ? (const void*)g_init.h_Gth_pinned
                                          : (const void*)g_init.h_Gth.data();
    hipMemcpyAsync(ghfall, src, (size_t)kNB * kML * 2, hipMemcpyHostToDevice, stream);
    Gh = ghfall;
  }
  const short* Gl = (const short*)g_init.d_Gtl;
  if (!Gl) {
    const void* src = g_init.h_Gtl_pinned ? (const void*)g_init.h_Gtl_pinned
                                          : (const void*)g_init.h_Gtl.data();
    hipMemcpyAsync(glfall, src, (size_t)kNB * kML * 2, hipMemcpyHostToDevice, stream);
    Gl = glfall;
  }

  // 0) dtype flag
  detect_kernel<<<1, 256, 0, stream>>>((const unsigned short*)q, flag);

  // prep: k, Wv -> bf16
  conv_bf16<<<(kML * kDM / 4 + 255) / 256, 256, 0, stream>>>(kmem, k_bf, kML * kDM / 4, flag);
  conv_bf16<<<(kDM * kDM / 4 + 255) / 256, 256, 0, stream>>>(Wv, Wv_bf, kDM * kDM / 4, flag);

  // exact f32 mu/sigma path
  gw_kernel<<<kML, 256, 0, stream>>>(GtTf, wmu, wsg, gw, flag);
  hipMemsetAsync(bw, 0, 2 * kDM * sizeof(float), stream);
  bwk_kernel<<<dim3(kDM / 256, kML / 32), 256, 0, stream>>>(kmem, gw, bw, flag);
  kw_kernel<<<kDM, 256, 0, stream>>>(Wk, bw, kw, flag);
  musig_kernel<<<kH * kQL / 4, 256, 0, stream>>>(q, kw, mu, sigsq, flag);

  // kv GEMM split-K=4: P[z][l][d] partials. 128x64 tiles -> 512 blocks (2/CU).
  mfma_gemm_sk<<<dim3(kDM / 64, kML / 128, 4), 256, 0, stream>>>(
      k_bf, kDM, Wv_bf, kDM, Pbuf, kDM);
  // reduce partials -> kvT[d][l] bf16 (single f2bf rounding, as before)
  reduceT_kernel<<<dim3(kDM / 64, kML / 64), 256, 0, stream>>>(Pbuf, kvT);

  // Wo -> bf16 (overlays Wv_bf, dead after kv GEMM)
  conv_bf16<<<(kDM * kDM / 4 + 255) / 256, 256, 0, stream>>>(Wo, Wo_bf, kDM * kDM / 4, flag);

  // valuesT[d][n] = sum_l kvT[d][l] * G[l][n]  (split G in, split VT out)
  // 64x64 tiles -> grid (16 n, 32 d) = 512 blocks (2/CU).
  mfma_gemm_bt2<<<dim3(kNB / 64, kDM / 64, 1), 256, 0, stream>>>(
      kvT, kML, Gh, Gl, kML, VTh, VTl, kNB, kML);

  // ctx[q][h*128+d'] = sum_n r(h,q,n) * valuesT[h*128+d'][n]  (3-pass split x split)
  // 64-row q-tiles -> grid (1, 32, 16) = 512 blocks (2/CU).
  mfma_rv<<<dim3(1, kQL / 64, kH), 256, 0, stream>>>(mu, sigsq, VTh, VTl, ctx);

  // out = ctx @ Wo^T  (runtime out dtype). 128x64 tiles -> grid (32, 16) = 512.
  mfma_gemm_bt<2><<<dim3(kDM / 64, kQL / 128, 1), 256, 0, stream>>>(
      ctx, kDM, 0, Wo_bf, kDM, 0, d_out, kDM, 0, kDM, flag);
}